// Round 8
// baseline (731.686 us; speedup 1.0000x reference)
//
#include <hip/hip_runtime.h>

// Problem constants (hardcoded; spatial_shapes = [[4,8]]*4)
//  bs=64, nq=64, E=256, Hn=8, dh=32, L=4, P=16, BEV=2, Pb=32
//  qb=128 collapses to 64 (queries duplicated). OFF col (h,f,c)=h*256+2f+c;
//  rp level = f&3; image level = f>>5 = wave; attn key = f;
//  output pairs (2q,2q+1) -> rows pj / pj+32.
//
// ws: [0,1M) Wtb bf16 [2048][256] | [1M,3M) Qb bf16 [4096][256]
//     [3M,5M) Khb bf16 [4096][256]
//
// mega2s9 (this round): ABLATION PROBE, output-correct. R0's mega2 verbatim,
// but Phase 3 (zero Am + bilinear scatter) runs 9x (idempotent: re-zero +
// re-scatter each rep; final Am identical; output exact). An opaque asm
// launder on acc each rep defeats LICM so the WHOLE phase re-executes.
// Phase-3 marginal cost = (dur - 91.6us)/8. Six structural theories are
// null (barriers/staging/occupancy/fusion/codesize/MLP); scatter is the one
// byte-identical invariant across all of them — measure it before touching.

typedef short  s16x8 __attribute__((ext_vector_type(8)));
typedef short  s16x4 __attribute__((ext_vector_type(4)));
typedef float  f32x4 __attribute__((ext_vector_type(4)));

__device__ __forceinline__ unsigned short f2bf(float f) {
    union { float f; unsigned u; } v; v.f = f;
    unsigned r = v.u + 0x7FFFu + ((v.u >> 16) & 1u);   // RNE
    return (unsigned short)(r >> 16);
}
__device__ __forceinline__ float bf2f(unsigned short u) {
    return __uint_as_float(((unsigned)u) << 16);
}

// ---------------------------------------------------------------------------
// prep: [0,512) W transpose f32->bf16 ; [512,1536) query->Qb ;
//       [1536,2560) key_hist->Khb   (unchanged, verified)
// ---------------------------------------------------------------------------
__global__ __launch_bounds__(256) void prep(
    const float* __restrict__ W, const float* __restrict__ query,
    const float* __restrict__ key_hist,
    short* __restrict__ Wtb, short* __restrict__ Qb, short* __restrict__ Khb)
{
    __shared__ float s[32][33];
    const int bx = blockIdx.x, t = threadIdx.x;
    if (bx < 512) {
        const int n0 = (bx & 63) * 32, k0 = (bx >> 6) * 32;
        const int c = t & 31, r0 = t >> 5;
        #pragma unroll
        for (int p = 0; p < 4; ++p) {
            const int r = r0 + p * 8;
            s[r][c] = W[(size_t)(k0 + r) * 2048 + n0 + c];
        }
        __syncthreads();
        #pragma unroll
        for (int p = 0; p < 4; ++p) {
            const int r = r0 + p * 8;
            Wtb[(size_t)(n0 + r) * 256 + k0 + c] = (short)f2bf(s[c][r]);
        }
    } else {
        const int j = bx - 512;
        const bool isK = j >= 1024;
        const float* src = isK ? key_hist : query;
        short* dst = isK ? Khb : Qb;
        const int i4 = ((j & 1023) * 256 + t) * 4;
        const float4 v = *(const float4*)(src + i4);
        s16x4 o;
        o.x = (short)f2bf(v.x); o.y = (short)f2bf(v.y);
        o.z = (short)f2bf(v.z); o.w = (short)f2bf(v.w);
        *(s16x4*)(dst + i4) = o;
    }
}

// ---------------------------------------------------------------------------
// mega2s9: one block per (h,b). LDS 63.5 KB -> 2 blocks/CU.
//          = R0 mega2 with Phase 3 executed 9x (probe), output-correct.
// ---------------------------------------------------------------------------
__global__ __launch_bounds__(256, 2) void mega2s9(
    const float* __restrict__ query, const float* __restrict__ value_hist,
    const float* __restrict__ refp,
    const short* __restrict__ Qb, const short* __restrict__ Khb,
    const short* __restrict__ Wtb, const float* __restrict__ bias,
    float* __restrict__ out)
{
    const int h = blockIdx.x, b = blockIdx.y;
    const int t = threadIdx.x, lane = t & 63, wave = t >> 6;
    const int quad = lane >> 4, col = lane & 15;
    const int wq = wave * 16;

    __shared__ __align__(16) short VTl[32 * 136];   // V^T [d][p], 8704 B
    __shared__ __align__(16) short attLb[64 * 136]; // att probs bf16, 17408 B
    __shared__ __align__(16) float rpsL[512];       // refp rows, 2048 B
    __shared__ __align__(16) float AmU[9216];       // 36864 B: Bsl / Am / Amb
    short* Bsl = (short*)AmU;                       // [4][64][72] bf16
    float* Am  = AmU;                               // [64][132] f32
    short* Amb = (short*)AmU;                       // [64][136] bf16

    // ================= Phase 0: stage VTl + rps =================
    {   // VTl[d][p]: values = [query rows | value_hist rows] h-slice, transposed
        const int p = t >> 1, hf = (t & 1) * 16;
        const float* src = ((p < 64) ? query : value_hist) +
                           (size_t)(b * 64 + (p & 63)) * 256 + h * 32 + hf;
        #pragma unroll
        for (int u = 0; u < 4; ++u) {
            const float4 v = *(const float4*)(src + 4 * u);
            VTl[(hf + 4 * u + 0) * 136 + p] = (short)f2bf(v.x);
            VTl[(hf + 4 * u + 1) * 136 + p] = (short)f2bf(v.y);
            VTl[(hf + 4 * u + 2) * 136 + p] = (short)f2bf(v.z);
            VTl[(hf + 4 * u + 3) * 136 + p] = (short)f2bf(v.w);
        }
    }
    rpsL[t]       = refp[(size_t)b * 512 + t];
    rpsL[t + 256] = refp[(size_t)b * 512 + t + 256];

    // ================= Phase 1: logits + softmax -> attLb =================
    {
        const s16x8 aq = *(const s16x8*)(Qb +
            ((size_t)b * 64 + wq + col) * 256 + h * 32 + quad * 8);
        f32x4 lacc[8];
        #pragma unroll
        for (int t8 = 0; t8 < 8; ++t8) {
            const short* src = (t8 < 4)
                ? (Qb  + ((size_t)b * 64 + 16 * t8 + col) * 256)
                : (Khb + ((size_t)b * 64 + 16 * (t8 - 4) + col) * 256);
            const s16x8 bk = *(const s16x8*)(src + h * 32 + quad * 8);
            const f32x4 z = {0.f, 0.f, 0.f, 0.f};
            lacc[t8] = __builtin_amdgcn_mfma_f32_16x16x32_bf16(aq, bk, z, 0, 0, 0);
        }
        #pragma unroll
        for (int r = 0; r < 4; ++r) {
            float m = lacc[0][r];
            #pragma unroll
            for (int t8 = 1; t8 < 8; ++t8) m = fmaxf(m, lacc[t8][r]);
            #pragma unroll
            for (int s = 1; s < 16; s <<= 1) m = fmaxf(m, __shfl_xor(m, s, 64));
            float e[8], ssum = 0.f;
            #pragma unroll
            for (int t8 = 0; t8 < 8; ++t8) {
                e[t8] = __expf(lacc[t8][r] - m); ssum += e[t8];
            }
            #pragma unroll
            for (int s = 1; s < 16; s <<= 1) ssum += __shfl_xor(ssum, s, 64);
            const float inv = 1.0f / ssum;
            const int q = wq + 4 * quad + r;
            #pragma unroll
            for (int t8 = 0; t8 < 8; ++t8)
                attLb[q * 136 + 16 * t8 + col] = (short)f2bf(e[t8] * inv);
        }
    }

    // ================= Phase 2: offsets GEMM (OFF in registers) =============
    // wave owns n' in [64*wave, +64): acc[mi][nj]; q = 16mi+4quad+reg,
    // n' = 64*wave + 16nj + col.
    f32x4 acc[4][4] = {};
    for (int kq = 0; kq < 4; ++kq) {
        s16x8 afp[4][2];                        // A-frags direct from Qb (L2)
        #pragma unroll
        for (int mi = 0; mi < 4; ++mi)
            #pragma unroll
            for (int ks = 0; ks < 2; ++ks)
                afp[mi][ks] = *(const s16x8*)(Qb +
                    ((size_t)b * 64 + 16 * mi + col) * 256
                    + kq * 64 + ks * 32 + quad * 8);
        #pragma unroll
        for (int u = 0; u < 8; ++u) {           // stage Bsl[4][64][72] <- Wtb
            const int g = t + 256 * u;
            const int w = g >> 9, rowu = (g >> 3) & 63, koff = (g & 7) * 8;
            *(s16x8*)&Bsl[(w * 64 + rowu) * 72 + koff] =
                *(const s16x8*)(Wtb + (size_t)(h * 256 + w * 64 + rowu) * 256
                                + kq * 64 + koff);
        }
        __syncthreads();
        #pragma unroll
        for (int ks = 0; ks < 2; ++ks) {
            s16x8 bf[4];
            #pragma unroll
            for (int nj = 0; nj < 4; ++nj)
                bf[nj] = *(const s16x8*)&Bsl[(wave * 64 + 16 * nj + col) * 72
                                             + ks * 32 + quad * 8];
            #pragma unroll
            for (int mi = 0; mi < 4; ++mi)
                #pragma unroll
                for (int nj = 0; nj < 4; ++nj)
                    acc[mi][nj] = __builtin_amdgcn_mfma_f32_16x16x32_bf16(
                        afp[mi][ks], bf[nj], acc[mi][nj], 0, 0, 0);
        }
        __syncthreads();
    }

    // ================= Phase 3 x9: zero Am, scatter (PROBE) ================
    #pragma unroll 1
    for (int rep = 0; rep < 9; ++rep) {
        // launder acc: opaque identity -> compiler must re-run the full
        // phase (address math, shfl, attLb reads) each rep, not just atomics
        #pragma unroll
        for (int mi = 0; mi < 4; ++mi)
            #pragma unroll
            for (int nj = 0; nj < 4; ++nj)
                #pragma unroll
                for (int r = 0; r < 4; ++r) {
                    float tv = acc[mi][nj][r];
                    asm volatile("" : "+v"(tv));
                    acc[mi][nj][r] = tv;
                }
        {
            #pragma unroll
            for (int u = 0; u < 33; ++u) AmU[t + 256 * u] = 0.f;
        }
        __syncthreads();
        {
            const int i   = col >> 1;          // f-sub 0..7 ; rp level = (f&3)
            const int par = col & 1;           // 0: regs {0,1}, 1: regs {2,3}
            const int base = 32 * wave;        // image level = f>>5 = wave
            #pragma unroll
            for (int nj = 0; nj < 4; ++nj) {
                const float bj = bias[h * 256 + wave * 64 + 16 * nj + col];
                const int f = 32 * wave + 8 * nj + i;
                #pragma unroll
                for (int mi = 0; mi < 4; ++mi) {
                    float v[4], p[4];
                    #pragma unroll
                    for (int r = 0; r < 4; ++r) v[r] = acc[mi][nj][r] + bj;
                    #pragma unroll
                    for (int r = 0; r < 4; ++r) p[r] = __shfl_xor(v[r], 1, 64);
                    #pragma unroll
                    for (int rs = 0; rs < 2; ++rs) {
                        const int r = par * 2 + rs;
                        const float ox = par ? p[r] : v[r];
                        const float oy = par ? v[r] : p[r];
                        const int q = 16 * mi + 4 * quad + r;
                        const float2 rp = *(const float2*)&rpsL[q * 8 + (i & 3) * 2];
                        const float a = bf2f((unsigned short)attLb[q * 136 + f]);
                        const float gx = 8.f * (rp.x + ox * 0.125f) - 0.5f;
                        const float gy = 4.f * (rp.y + oy * 0.25f) - 0.5f;
                        const float x0f = floorf(gx), y0f = floorf(gy);
                        const float wx = gx - x0f, wy = gy - y0f;
                        const int x0 = (int)x0f, y0 = (int)y0f;
                        float* rowW = &Am[q * 132 + base];
                        const bool xv0 = (x0 >= 0) && (x0 < 8);
                        const bool xv1 = (x0 >= -1) && (x0 < 7);
                        const bool yv0 = (y0 >= 0) && (y0 < 4);
                        const bool yv1 = (y0 >= -1) && (y0 < 3);
                        if (xv0 && yv0) unsafeAtomicAdd(&rowW[y0 * 8 + x0],           a * (1.f - wx) * (1.f - wy));
                        if (xv1 && yv0) unsafeAtomicAdd(&rowW[y0 * 8 + x0 + 1],       a * wx * (1.f - wy));
                        if (xv0 && yv1) unsafeAtomicAdd(&rowW[(y0 + 1) * 8 + x0],     a * (1.f - wx) * wy);
                        if (xv1 && yv1) unsafeAtomicAdd(&rowW[(y0 + 1) * 8 + x0 + 1], a * wx * wy);
                    }
                }
            }
        }
        __syncthreads();
    }

    // ================= Phase 4: Am -> bf16, AV, output =================
    {
        const int cq = t >> 2, cc = (t & 3) * 32;
        float vreg[32];
        #pragma unroll
        for (int u = 0; u < 8; ++u) {
            const float4 v = *(const float4*)&Am[cq * 132 + cc + 4 * u];
            vreg[4 * u + 0] = v.x; vreg[4 * u + 1] = v.y;
            vreg[4 * u + 2] = v.z; vreg[4 * u + 3] = v.w;
        }
        __syncthreads();
        #pragma unroll
        for (int u = 0; u < 4; ++u) {
            s16x8 o;
            #pragma unroll
            for (int j = 0; j < 8; ++j) o[j] = (short)f2bf(vreg[u * 8 + j]);
            *(s16x8*)&Amb[cq * 136 + cc + u * 8] = o;
        }
    }
    __syncthreads();
    {
        f32x4 oacc[2] = {};
        #pragma unroll
        for (int ks = 0; ks < 4; ++ks) {
            const s16x8 af = *(const s16x8*)&Amb[(wq + col) * 136 + ks * 32 + quad * 8];
            #pragma unroll
            for (int n2 = 0; n2 < 2; ++n2) {
                const s16x8 bv = *(const s16x8*)&VTl[(n2 * 16 + col) * 136
                                                     + ks * 32 + quad * 8];
                oacc[n2] = __builtin_amdgcn_mfma_f32_16x16x32_bf16(af, bv, oacc[n2], 0, 0, 0);
            }
        }
        #pragma unroll
        for (int n2 = 0; n2 < 2; ++n2) {
            const int d = h * 32 + n2 * 16 + col;
            #pragma unroll
            for (int pr = 0; pr < 2; ++pr) {
                const float avg = 0.5f * (oacc[n2][2 * pr] + oacc[n2][2 * pr + 1]);
                const int pj = wave * 8 + quad * 2 + pr;
                const size_t re = ((size_t)b * 64 + pj) * 256 + d;
                const size_t ro = ((size_t)b * 64 + pj + 32) * 256 + d;
                out[re] = query[re] + avg;
                out[ro] = query[ro] + avg;
            }
        }
    }
}

extern "C" void kernel_launch(void* const* d_in, const int* in_sizes, int n_in,
                              void* d_out, int out_size, void* d_ws, size_t ws_size,
                              hipStream_t stream) {
    (void)in_sizes; (void)n_in; (void)out_size; (void)ws_size;
    const float* query      = (const float*)d_in[0];
    const float* key_hist   = (const float*)d_in[1];
    const float* value_hist = (const float*)d_in[2];
    const float* refp       = (const float*)d_in[3];
    const float* W_off      = (const float*)d_in[5];
    const float* b_off      = (const float*)d_in[6];

    char* ws = (char*)d_ws;
    short* Wtb = (short*)(ws);                 // 1 MB
    short* Qb  = (short*)(ws + (1u << 20));    // 2 MB
    short* Khb = (short*)(ws + (3u << 20));    // 2 MB
    float* out = (float*)d_out;

    prep<<<2560, 256, 0, stream>>>(W_off, query, key_hist, Wtb, Qb, Khb);
    mega2s9<<<dim3(8, 64), 256, 0, stream>>>(query, value_hist, refp,
                                             Qb, Khb, Wtb, b_off, out);
}